// Round 9
// baseline (484.634 us; speedup 1.0000x reference)
//
#include <hip/hip_runtime.h>
#include <math.h>

#define NN 50000
#define NE 800000
#define DD 128
#define NBK 782          // buckets = dst>>6, 64 nodes each
#define BIN_CHUNK 4096   // edges per k_bin block
#define BIN_NB 196       // ceil(800000/4096)
#define AGR_CAP 1536     // staged edges per bucket (mean 1023, sigma ~32)
#define HREP 16          // hist replicas
#define CREP 64          // colsum/sumsq replicas
#define CVT_NB 3125      // 800000 groups of 8 elems / 256 thr
#define HIST_NB 196      // ceil(800000/4096)
#define PACK_NB 16       // 4096 pack items / 256 thr
#define PRE_NB (CVT_NB + HIST_NB + PACK_NB)

typedef short bf16x8 __attribute__((ext_vector_type(8)));
typedef unsigned short us8 __attribute__((ext_vector_type(8)));
typedef float f32x4 __attribute__((ext_vector_type(4)));

__device__ __forceinline__ unsigned short f2bf(float x) {
    unsigned int u = __float_as_uint(x);
    u += 0x7fffu + ((u >> 16) & 1u);
    return (unsigned short)(u >> 16);
}
__device__ __forceinline__ float bf2f(unsigned short h) {
    return __uint_as_float(((unsigned int)h) << 16);
}

// ---- K0: fused cvt + bucket hist + W pack; last block does bucket scan ------
__global__ __launch_bounds__(256) void k_pre(const float* __restrict__ feat,
                                             unsigned short* __restrict__ featb,
                                             const int* __restrict__ dst,
                                             int* __restrict__ ghist,
                                             const float* __restrict__ Wneigh,
                                             const float* __restrict__ Wself,
                                             const float* __restrict__ bself,
                                             const float* __restrict__ bias,
                                             unsigned short* __restrict__ Wpk,
                                             float* __restrict__ bcomb,
                                             int* __restrict__ bbase,
                                             int* __restrict__ bcursor,
                                             int* __restrict__ donecnt) {
    __shared__ int lh[NBK];
    __shared__ int part[256];
    __shared__ int lastflag;
    const int t = threadIdx.x;
    const int bid = blockIdx.x;

    if (bid < CVT_NB) {
        int idx = bid * 256 + t;  // < 800000
        float4 a = ((const float4*)feat)[idx * 2];
        float4 b = ((const float4*)feat)[idx * 2 + 1];
        us8 o;
        o[0] = f2bf(a.x); o[1] = f2bf(a.y); o[2] = f2bf(a.z); o[3] = f2bf(a.w);
        o[4] = f2bf(b.x); o[5] = f2bf(b.y); o[6] = f2bf(b.z); o[7] = f2bf(b.w);
        *(us8*)(featb + (size_t)idx * 8) = o;
    } else if (bid < CVT_NB + HIST_NB) {
        int hb = bid - CVT_NB;
        for (int i = t; i < NBK; i += 256) lh[i] = 0;
        __syncthreads();
        int base = hb * 4096;
        int* grep = ghist + (hb & (HREP - 1)) * (NBK + 1);
#pragma unroll
        for (int k = 0; k < 16; k++) {
            int e = base + k * 256 + t;
            if (e < NE) atomicAdd(&lh[dst[e] >> 6], 1);
        }
        __syncthreads();
        for (int i = t; i < NBK; i += 256)
            if (lh[i]) atomicAdd(&grep[i], lh[i]);
    } else {
        int idx = (bid - CVT_NB - HIST_NB) * 256 + t;  // 0..4095
        int ks = idx >> 9;
        int ct = (idx >> 6) & 7;
        int lane = idx & 63;
        int quad = lane >> 4, l16 = lane & 15;
        int c = ct * 16 + l16;
        int kb = ks * 32 + quad * 8;
        const float* srcw = (kb < 128) ? (Wself + (size_t)c * DD + kb)
                                       : (Wneigh + (size_t)c * DD + (kb - 128));
        float4 x0 = *(const float4*)srcw;
        float4 x1 = *(const float4*)(srcw + 4);
        us8 o;
        o[0] = f2bf(x0.x); o[1] = f2bf(x0.y); o[2] = f2bf(x0.z); o[3] = f2bf(x0.w);
        o[4] = f2bf(x1.x); o[5] = f2bf(x1.y); o[6] = f2bf(x1.z); o[7] = f2bf(x1.w);
        *(us8*)(Wpk + (size_t)idx * 8) = o;
        if (idx < DD) bcomb[idx] = bself[idx] + bias[idx];
    }

    // completion detection: last block performs the bucket scan
    __syncthreads();
    __threadfence();
    if (t == 0) lastflag = (atomicAdd(donecnt, 1) == PRE_NB - 1) ? 1 : 0;
    __syncthreads();
    if (lastflag) {
        int v[4];
        int s = 0;
#pragma unroll
        for (int k = 0; k < 4; k++) {
            int i = t * 4 + k;
            int x = 0;
            if (i < NBK) {
#pragma unroll
                for (int h = 0; h < HREP; h++)
                    x += __hip_atomic_load(&ghist[h * (NBK + 1) + i], __ATOMIC_RELAXED,
                                           __HIP_MEMORY_SCOPE_AGENT);
            }
            v[k] = x;
            s += x;
        }
        part[t] = s;
        __syncthreads();
        for (int off = 1; off < 256; off <<= 1) {
            int x = part[t];
            int a = (t >= off) ? part[t - off] : 0;
            __syncthreads();
            part[t] = x + a;
            __syncthreads();
        }
        int ex = part[t] - s;
#pragma unroll
        for (int k = 0; k < 4; k++) {
            int i = t * 4 + k;
            if (i < NBK) {
                bbase[i] = ex;
                bcursor[i] = ex;
            }
            ex += v[k];
        }
        if (t == 255) bbase[NBK] = part[255];
    }
}

// ---- K1: multisplit bin (LDS-staged, coalesced runs), 196 blocks ------------
__global__ __launch_bounds__(512) void k_bin(const int* __restrict__ src,
                                             const int* __restrict__ dst,
                                             const float* __restrict__ w,
                                             int* __restrict__ bcursor,
                                             int2* __restrict__ binned) {
    __shared__ int2 staged[BIN_CHUNK];                        // 32 KB
    __shared__ int lh[NBK], le[NBK], lcur[NBK], runbase[NBK]; // 12.5 KB
    __shared__ int part[512];                                 // 2 KB
    const int t = threadIdx.x;
    const int base = blockIdx.x * BIN_CHUNK;
    const int cnt = min(BIN_CHUNK, NE - base);

    for (int i = t; i < NBK; i += 512) lh[i] = 0;
    __syncthreads();

    int2 rec[8];
    int rbk[8];
#pragma unroll
    for (int k = 0; k < 8; k++) {
        int e = base + k * 512 + t;
        rbk[k] = -1;
        if (e < NE) {
            int d = dst[e];
            int b = d >> 6;
            rbk[k] = b;
            rec[k].x = __float_as_int(w[e]);
            rec[k].y = (src[e] & 0xFFFF) | ((d & 63) << 16) | (b << 22);
            atomicAdd(&lh[b], 1);
        }
    }
    __syncthreads();
    // scan 782 counts via pairs
    int i0 = 2 * t, i1 = 2 * t + 1;
    int h0 = (i0 < NBK) ? lh[i0] : 0;
    int h1 = (i1 < NBK) ? lh[i1] : 0;
    int s = h0 + h1;
    part[t] = s;
    __syncthreads();
    for (int off = 1; off < 512; off <<= 1) {
        int x = part[t];
        int a = (t >= off) ? part[t - off] : 0;
        __syncthreads();
        part[t] = x + a;
        __syncthreads();
    }
    int ex = part[t] - s;
    if (i0 < NBK) {
        le[i0] = ex;
        lcur[i0] = ex;
        runbase[i0] = h0 ? atomicAdd(&bcursor[i0], h0) : 0;
    }
    if (i1 < NBK) {
        le[i1] = ex + h0;
        lcur[i1] = ex + h0;
        runbase[i1] = h1 ? atomicAdd(&bcursor[i1], h1) : 0;
    }
    __syncthreads();
#pragma unroll
    for (int k = 0; k < 8; k++) {
        if (rbk[k] >= 0) {
            int p = atomicAdd(&lcur[rbk[k]], 1);
            staged[p] = rec[k];
        }
    }
    __syncthreads();
#pragma unroll
    for (int k = 0; k < 8; k++) {
        int sidx = k * 512 + t;
        if (sidx < cnt) {
            int2 r = staged[sidx];
            int b = ((unsigned int)r.y) >> 22;
            binned[runbase[b] + (sidx - le[b])] = r;
        }
    }
}

// ---- K2: per-bucket sort + aggregation (512 thr, 64 nodes, 1-pass load) -----
__global__ __launch_bounds__(512) void k_aggr2(const unsigned short* __restrict__ featb,
                                               const int* __restrict__ bbase,
                                               const int2* __restrict__ binned,
                                               unsigned short* __restrict__ nrmb) {
    __shared__ int2 sstore[AGR_CAP];   // 12 KB
    __shared__ int lcnt[64], arr[64], loff[65], lcur[64];
    const int t = threadIdx.x;
    const int b = blockIdx.x;
    const int j0 = bbase[b];
    const int cnt = min(bbase[b + 1] - j0, AGR_CAP);

    if (t < 64) lcnt[t] = 0;
    __syncthreads();
    // phase A: single-pass load into regs + histogram by local dst
    int2 rc[3];
    int rld[3];
#pragma unroll
    for (int k = 0; k < 3; k++) {
        int s = t + k * 512;
        rld[k] = -1;
        if (s < cnt) {
            rc[k] = binned[j0 + s];
            rld[k] = (((unsigned int)rc[k].y) >> 16) & 63;
            atomicAdd(&lcnt[rld[k]], 1);
        }
    }
    __syncthreads();
    int cv = (t < 64) ? lcnt[t] : 0;
    if (t < 64) arr[t] = cv;
    __syncthreads();
    for (int off = 1; off < 64; off <<= 1) {
        int x = 0, a = 0;
        if (t < 64) {
            x = arr[t];
            a = (t >= off) ? arr[t - off] : 0;
        }
        __syncthreads();
        if (t < 64) arr[t] = x + a;
        __syncthreads();
    }
    if (t < 64) {
        loff[t] = arr[t] - cv;
        lcur[t] = arr[t] - cv;
    }
    if (t == 63) loff[64] = arr[63];
    __syncthreads();
    // phase B: scatter regs into LDS sorted by local dst
#pragma unroll
    for (int k = 0; k < 3; k++) {
        if (rld[k] >= 0) {
            int p = atomicAdd(&lcur[rld[k]], 1);
            sstore[p] = rc[k];
        }
    }
    __syncthreads();
    // phase C: 8 waves x 8 nodes; per node 16 lanes x 4 edge-slots in flight
    const int wv = t >> 6, lane = t & 63;
    const int grp = lane >> 4, l16 = lane & 15;
#pragma unroll
    for (int i = 0; i < 8; i++) {
        int n = wv * 8 + i;
        int node = b * 64 + n;
        int e0 = loff[n], e1 = loff[n + 1];
        float a0 = 0.f, a1 = 0.f, a2 = 0.f, a3 = 0.f;
        float a4 = 0.f, a5 = 0.f, a6 = 0.f, a7 = 0.f;
        float wsum = 0.f;
        for (int j = e0 + grp; j < e1; j += 4) {
            int2 r = sstore[j];
            float wvv = __int_as_float(r.x);
            int srcn = r.y & 0xFFFF;
            const us8 f = *(const us8*)(featb + (size_t)srcn * DD + l16 * 8);
            a0 = fmaf(bf2f(f[0]), wvv, a0);
            a1 = fmaf(bf2f(f[1]), wvv, a1);
            a2 = fmaf(bf2f(f[2]), wvv, a2);
            a3 = fmaf(bf2f(f[3]), wvv, a3);
            a4 = fmaf(bf2f(f[4]), wvv, a4);
            a5 = fmaf(bf2f(f[5]), wvv, a5);
            a6 = fmaf(bf2f(f[6]), wvv, a6);
            a7 = fmaf(bf2f(f[7]), wvv, a7);
            wsum += wvv;
        }
        float acc[8] = {a0, a1, a2, a3, a4, a5, a6, a7};
#pragma unroll
        for (int k = 0; k < 8; k++) {
            acc[k] += __shfl_xor(acc[k], 16);
            acc[k] += __shfl_xor(acc[k], 32);
        }
        wsum += __shfl_xor(wsum, 16);
        wsum += __shfl_xor(wsum, 32);
        if (grp == 0 && node < NN) {
            float inv = 1.0f / (wsum + 1e-8f);
            us8 o;
#pragma unroll
            for (int k = 0; k < 8; k++) o[k] = f2bf(acc[k] * inv);
            *(us8*)(nrmb + (size_t)node * DD + l16 * 8) = o;
        }
    }
}

// ---- K3: MFMA GEMM + bias/ReLU + BN partials; last block finalizes BN -------
__global__ __launch_bounds__(256) void k_gemm(const unsigned short* __restrict__ featb,
                                              const unsigned short* __restrict__ nrmb,
                                              const unsigned short* __restrict__ Wpk,
                                              const float* __restrict__ bcomb,
                                              unsigned short* __restrict__ rstb,
                                              float* __restrict__ colrep,
                                              const float* __restrict__ gamma,
                                              const float* __restrict__ beta,
                                              float* __restrict__ scale,
                                              float* __restrict__ shift,
                                              int* __restrict__ donecnt) {
    __shared__ unsigned short sW[16384];  // 32 KB: one K-half of packed W
    __shared__ float pS[4][128];
    __shared__ float pQ[4][128];
    __shared__ int lastg;
    const int tid = threadIdx.x;
    const int wv = tid >> 6, lane = tid & 63;
    const int quad = lane >> 4, l16 = lane & 15;
    const int rowA = blockIdx.x * 64 + wv * 16 + l16;
    const bool validA = rowA < NN;

    f32x4 acc[8];
#pragma unroll
    for (int ct = 0; ct < 8; ct++) acc[ct] = (f32x4){0.f, 0.f, 0.f, 0.f};

#pragma unroll
    for (int half = 0; half < 2; half++) {
        const unsigned short* xb = half ? nrmb : featb;
        bf16x8 a[4];
#pragma unroll
        for (int k4 = 0; k4 < 4; k4++) {
            a[k4] = (bf16x8){0, 0, 0, 0, 0, 0, 0, 0};
            if (validA) a[k4] = *(const bf16x8*)(xb + (size_t)rowA * DD + k4 * 32 + quad * 8);
        }
        if (half) __syncthreads();
#pragma unroll
        for (int p = 0; p < 8; p++) {
            *(us8*)(sW + p * 2048 + tid * 8) =
                *(const us8*)(Wpk + half * 16384 + p * 2048 + tid * 8);
        }
        __syncthreads();
#pragma unroll
        for (int k4 = 0; k4 < 4; k4++) {
#pragma unroll
            for (int ct = 0; ct < 8; ct++) {
                bf16x8 bfr = *(const bf16x8*)(sW + ((k4 * 8 + ct) * 64 + lane) * 8);
                acc[ct] = __builtin_amdgcn_mfma_f32_16x16x32_bf16(a[k4], bfr, acc[ct], 0, 0, 0);
            }
        }
    }

    const int rowC = blockIdx.x * 64 + wv * 16 + quad * 4;
    float s[8], q[8];
#pragma unroll
    for (int ct = 0; ct < 8; ct++) {
        const int c = ct * 16 + l16;
        const float bb = bcomb[c];
        float ls = 0.f, lq = 0.f;
#pragma unroll
        for (int r = 0; r < 4; r++) {
            float v = acc[ct][r] + bb;
            v = v > 0.f ? v : 0.f;
            if (rowC + r < NN) {
                rstb[(size_t)(rowC + r) * DD + c] = f2bf(v);
                ls += v;
                lq += v * v;
            }
        }
        s[ct] = ls;
        q[ct] = lq;
    }
#pragma unroll
    for (int ct = 0; ct < 8; ct++) {
        s[ct] += __shfl_xor(s[ct], 16);
        s[ct] += __shfl_xor(s[ct], 32);
        q[ct] += __shfl_xor(q[ct], 16);
        q[ct] += __shfl_xor(q[ct], 32);
    }
    if (quad == 0) {
#pragma unroll
        for (int ct = 0; ct < 8; ct++) {
            pS[wv][ct * 16 + l16] = s[ct];
            pQ[wv][ct * 16 + l16] = q[ct];
        }
    }
    __syncthreads();
    if (tid < 128) {
        float* rep = colrep + (blockIdx.x & (CREP - 1)) * 256;
        float ts = pS[0][tid] + pS[1][tid] + pS[2][tid] + pS[3][tid];
        float tq = pQ[0][tid] + pQ[1][tid] + pQ[2][tid] + pQ[3][tid];
        atomicAdd(&rep[tid], ts);
        atomicAdd(&rep[128 + tid], tq);
    }
    // last block finalizes BN scale/shift
    __syncthreads();
    __threadfence();
    if (tid == 0) lastg = (atomicAdd(donecnt, 1) == (int)gridDim.x - 1) ? 1 : 0;
    __syncthreads();
    if (lastg && tid < 128) {
        float ts = 0.f, tq = 0.f;
#pragma unroll
        for (int r = 0; r < CREP; r++) {
            ts += __hip_atomic_load(&colrep[r * 256 + tid], __ATOMIC_RELAXED,
                                    __HIP_MEMORY_SCOPE_AGENT);
            tq += __hip_atomic_load(&colrep[r * 256 + 128 + tid], __ATOMIC_RELAXED,
                                    __HIP_MEMORY_SCOPE_AGENT);
        }
        float mu = ts * (1.0f / NN);
        float var = tq * (1.0f / NN) - mu * mu;
        float sc = gamma[tid] * rsqrtf(var + 1e-5f);
        scale[tid] = sc;
        shift[tid] = beta[tid] - mu * sc;
    }
}

// ---- K4: apply BN (bf16 rst -> fp32 out) ------------------------------------
__global__ void k_apply(const unsigned short* __restrict__ rstb,
                        const float* __restrict__ scale, const float* __restrict__ shift,
                        float* __restrict__ out) {
    int idx = blockIdx.x * 256 + threadIdx.x;
    if (idx < NN * DD / 8) {
        us8 v = *(const us8*)(rstb + (size_t)idx * 8);
        int c8 = (idx & 15) * 8;
        float4 s0 = *(const float4*)(scale + c8);
        float4 s1 = *(const float4*)(scale + c8 + 4);
        float4 h0 = *(const float4*)(shift + c8);
        float4 h1 = *(const float4*)(shift + c8 + 4);
        float4 o0, o1;
        o0.x = fmaf(bf2f(v[0]), s0.x, h0.x);
        o0.y = fmaf(bf2f(v[1]), s0.y, h0.y);
        o0.z = fmaf(bf2f(v[2]), s0.z, h0.z);
        o0.w = fmaf(bf2f(v[3]), s0.w, h0.w);
        o1.x = fmaf(bf2f(v[4]), s1.x, h1.x);
        o1.y = fmaf(bf2f(v[5]), s1.y, h1.y);
        o1.z = fmaf(bf2f(v[6]), s1.z, h1.z);
        o1.w = fmaf(bf2f(v[7]), s1.w, h1.w);
        ((float4*)out)[idx * 2] = o0;
        ((float4*)out)[idx * 2 + 1] = o1;
    }
}

extern "C" void kernel_launch(void* const* d_in, const int* in_sizes, int n_in,
                              void* d_out, int out_size, void* d_ws, size_t ws_size,
                              hipStream_t stream) {
    const float* feat = (const float*)d_in[0];
    const int* src = (const int*)d_in[1];
    const int* dst = (const int*)d_in[2];
    const float* ew = (const float*)d_in[3];
    const float* Wneigh = (const float*)d_in[4];
    const float* Wself = (const float*)d_in[5];
    const float* bself = (const float*)d_in[6];
    const float* bias = (const float*)d_in[7];
    const float* gamma = (const float*)d_in[8];
    const float* beta = (const float*)d_in[9];
    float* out = (float*)d_out;

    float* ws = (float*)d_ws;
    unsigned short* featb = (unsigned short*)ws;             // 6.4M bf16
    unsigned short* nrmb = (unsigned short*)(ws + 3200000);  // 6.4M bf16
    unsigned short* Wpk = (unsigned short*)(ws + 6400000);   // 32768 bf16
    float* bcomb = ws + 6416384;                             // 128
    float* scale = bcomb + 128;                              // 128
    float* shift = scale + 128;                              // 128
    int* ghist = (int*)(shift + 128);                        // 16*783  [zeroed]
    float* colrep = (float*)(ghist + HREP * (NBK + 1));      // 64*256  [zeroed]
    int* dcnt = (int*)(colrep + CREP * 256);                 // 2       [zeroed]
    int* bbase = dcnt + 2;                                   // 783
    int* bcursor = bbase + 783;                              // 782 (+1 pad)
    int2* binned = (int2*)(bcursor + 784);                   // 800000 x 8B
    unsigned short* rstb = featb;  // alias: gemm reads/writes same rows per tile

    hipMemsetAsync(ghist, 0, (HREP * (NBK + 1) + CREP * 256 + 2) * sizeof(int), stream);

    k_pre<<<PRE_NB, 256, 0, stream>>>(feat, featb, dst, ghist, Wneigh, Wself, bself,
                                      bias, Wpk, bcomb, bbase, bcursor, &dcnt[0]);
    k_bin<<<BIN_NB, 512, 0, stream>>>(src, dst, ew, bcursor, binned);
    k_aggr2<<<NBK, 512, 0, stream>>>(featb, bbase, binned, nrmb);
    k_gemm<<<(NN + 63) / 64, 256, 0, stream>>>(featb, nrmb, Wpk, bcomb, rstb, colrep,
                                               gamma, beta, scale, shift, &dcnt[1]);
    k_apply<<<(NN * DD / 8 + 255) / 256, 256, 0, stream>>>(rstb, scale, shift, out);
}

// Round 10
// 177.687 us; speedup vs baseline: 2.7275x; 2.7275x over previous
//
#include <hip/hip_runtime.h>
#include <math.h>

#define NN 50000
#define NE 800000
#define DD 128
#define NBK 782          // buckets = dst>>6, 64 nodes each
#define BIN_CHUNK 4096   // edges per k_bin block
#define BIN_NB 196       // ceil(800000/4096)
#define AGR_CAP 1536     // staged edges per bucket (mean 1023, sigma ~32)
#define HREP 16          // hist replicas
#define CREP 64          // colsum/sumsq replicas
#define CVT_NB 3125      // 800000 groups of 8 elems / 256 thr
#define HIST_NB 196      // ceil(800000/4096)

typedef short bf16x8 __attribute__((ext_vector_type(8)));
typedef unsigned short us8 __attribute__((ext_vector_type(8)));
typedef float f32x4 __attribute__((ext_vector_type(4)));

__device__ __forceinline__ unsigned short f2bf(float x) {
    unsigned int u = __float_as_uint(x);
    u += 0x7fffu + ((u >> 16) & 1u);
    return (unsigned short)(u >> 16);
}
__device__ __forceinline__ float bf2f(unsigned short h) {
    return __uint_as_float(((unsigned int)h) << 16);
}

// ---- K0: fused fp32->bf16 convert + bucket histogram ------------------------
__global__ __launch_bounds__(256) void k_pre(const float* __restrict__ feat,
                                             unsigned short* __restrict__ featb,
                                             const int* __restrict__ dst,
                                             int* __restrict__ ghist) {
    __shared__ int lh[NBK];
    const int t = threadIdx.x;
    if (blockIdx.x < CVT_NB) {
        int idx = blockIdx.x * 256 + t;  // < 800000
        float4 a = ((const float4*)feat)[idx * 2];
        float4 b = ((const float4*)feat)[idx * 2 + 1];
        us8 o;
        o[0] = f2bf(a.x); o[1] = f2bf(a.y); o[2] = f2bf(a.z); o[3] = f2bf(a.w);
        o[4] = f2bf(b.x); o[5] = f2bf(b.y); o[6] = f2bf(b.z); o[7] = f2bf(b.w);
        *(us8*)(featb + (size_t)idx * 8) = o;
    } else {
        int hb = blockIdx.x - CVT_NB;
        for (int i = t; i < NBK; i += 256) lh[i] = 0;
        __syncthreads();
        int base = hb * 4096;
        int* grep = ghist + (hb & (HREP - 1)) * (NBK + 1);
#pragma unroll
        for (int k = 0; k < 16; k++) {
            int e = base + k * 256 + t;
            if (e < NE) atomicAdd(&lh[dst[e] >> 6], 1);
        }
        __syncthreads();
        for (int i = t; i < NBK; i += 256)
            if (lh[i]) atomicAdd(&grep[i], lh[i]);
    }
}

// ---- K1: fused bucket scan (block 0) + W pack (blocks 1..8) -----------------
__global__ __launch_bounds__(512) void k_scanp(const int* __restrict__ ghist,
                                               int* __restrict__ bbase,
                                               int* __restrict__ bcursor,
                                               const float* __restrict__ Wneigh,
                                               const float* __restrict__ Wself,
                                               const float* __restrict__ bself,
                                               const float* __restrict__ bias,
                                               unsigned short* __restrict__ Wpk,
                                               float* __restrict__ bcomb) {
    const int t = threadIdx.x;
    if (blockIdx.x == 0) {
        __shared__ int part[512];
        int i0 = 2 * t, i1 = 2 * t + 1;
        int v0 = 0, v1 = 0;
        if (i0 < NBK) {
#pragma unroll
            for (int h = 0; h < HREP; h++) v0 += ghist[h * (NBK + 1) + i0];
        }
        if (i1 < NBK) {
#pragma unroll
            for (int h = 0; h < HREP; h++) v1 += ghist[h * (NBK + 1) + i1];
        }
        int s = v0 + v1;
        part[t] = s;
        __syncthreads();
        for (int off = 1; off < 512; off <<= 1) {
            int x = part[t];
            int a = (t >= off) ? part[t - off] : 0;
            __syncthreads();
            part[t] = x + a;
            __syncthreads();
        }
        int ex = part[t] - s;
        if (i0 <= NBK) {
            bbase[i0] = ex;
            if (i0 < NBK) bcursor[i0] = ex;
        }
        if (i1 <= NBK) {
            bbase[i1] = ex + v0;
            if (i1 < NBK) bcursor[i1] = ex + v0;
        }
    } else {
        int idx = (blockIdx.x - 1) * 512 + t;  // 0..4095
        int ks = idx >> 9;
        int ct = (idx >> 6) & 7;
        int lane = idx & 63;
        int quad = lane >> 4, l16 = lane & 15;
        int c = ct * 16 + l16;
        int kb = ks * 32 + quad * 8;
        const float* srcw = (kb < 128) ? (Wself + (size_t)c * DD + kb)
                                       : (Wneigh + (size_t)c * DD + (kb - 128));
        float4 x0 = *(const float4*)srcw;
        float4 x1 = *(const float4*)(srcw + 4);
        us8 o;
        o[0] = f2bf(x0.x); o[1] = f2bf(x0.y); o[2] = f2bf(x0.z); o[3] = f2bf(x0.w);
        o[4] = f2bf(x1.x); o[5] = f2bf(x1.y); o[6] = f2bf(x1.z); o[7] = f2bf(x1.w);
        *(us8*)(Wpk + (size_t)idx * 8) = o;
        if (idx < DD) bcomb[idx] = bself[idx] + bias[idx];
    }
}

// ---- K2: multisplit bin (LDS-staged, coalesced runs), 196 blocks ------------
__global__ __launch_bounds__(512) void k_bin(const int* __restrict__ src,
                                             const int* __restrict__ dst,
                                             const float* __restrict__ w,
                                             int* __restrict__ bcursor,
                                             int2* __restrict__ binned) {
    __shared__ int2 staged[BIN_CHUNK];                        // 32 KB
    __shared__ int lh[NBK], le[NBK], lcur[NBK], runbase[NBK]; // 12.5 KB
    __shared__ int part[512];                                 // 2 KB
    const int t = threadIdx.x;
    const int base = blockIdx.x * BIN_CHUNK;
    const int cnt = min(BIN_CHUNK, NE - base);

    for (int i = t; i < NBK; i += 512) lh[i] = 0;
    __syncthreads();

    int2 rec[8];
    int rbk[8];
#pragma unroll
    for (int k = 0; k < 8; k++) {
        int e = base + k * 512 + t;
        rbk[k] = -1;
        if (e < NE) {
            int d = dst[e];
            int b = d >> 6;
            rbk[k] = b;
            rec[k].x = __float_as_int(w[e]);
            rec[k].y = (src[e] & 0xFFFF) | ((d & 63) << 16) | (b << 22);
            atomicAdd(&lh[b], 1);
        }
    }
    __syncthreads();
    int i0 = 2 * t, i1 = 2 * t + 1;
    int h0 = (i0 < NBK) ? lh[i0] : 0;
    int h1 = (i1 < NBK) ? lh[i1] : 0;
    int s = h0 + h1;
    part[t] = s;
    __syncthreads();
    for (int off = 1; off < 512; off <<= 1) {
        int x = part[t];
        int a = (t >= off) ? part[t - off] : 0;
        __syncthreads();
        part[t] = x + a;
        __syncthreads();
    }
    int ex = part[t] - s;
    if (i0 < NBK) {
        le[i0] = ex;
        lcur[i0] = ex;
        runbase[i0] = h0 ? atomicAdd(&bcursor[i0], h0) : 0;
    }
    if (i1 < NBK) {
        le[i1] = ex + h0;
        lcur[i1] = ex + h0;
        runbase[i1] = h1 ? atomicAdd(&bcursor[i1], h1) : 0;
    }
    __syncthreads();
#pragma unroll
    for (int k = 0; k < 8; k++) {
        if (rbk[k] >= 0) {
            int p = atomicAdd(&lcur[rbk[k]], 1);
            staged[p] = rec[k];
        }
    }
    __syncthreads();
#pragma unroll
    for (int k = 0; k < 8; k++) {
        int sidx = k * 512 + t;
        if (sidx < cnt) {
            int2 r = staged[sidx];
            int b = ((unsigned int)r.y) >> 22;
            binned[runbase[b] + (sidx - le[b])] = r;
        }
    }
}

// ---- K3: per-bucket sort + aggregation (512 thr, 64 nodes, 1-pass load) -----
__global__ __launch_bounds__(512) void k_aggr2(const unsigned short* __restrict__ featb,
                                               const int* __restrict__ bbase,
                                               const int2* __restrict__ binned,
                                               unsigned short* __restrict__ nrmb) {
    __shared__ int2 sstore[AGR_CAP];   // 12 KB
    __shared__ int lcnt[64], arr[64], loff[65], lcur[64];
    const int t = threadIdx.x;
    const int b = blockIdx.x;
    const int j0 = bbase[b];
    const int cnt = min(bbase[b + 1] - j0, AGR_CAP);

    if (t < 64) lcnt[t] = 0;
    __syncthreads();
    // phase A: single-pass load into regs + histogram by local dst
    int2 rc[3];
    int rld[3];
#pragma unroll
    for (int k = 0; k < 3; k++) {
        int s = t + k * 512;
        rld[k] = -1;
        if (s < cnt) {
            rc[k] = binned[j0 + s];
            rld[k] = (((unsigned int)rc[k].y) >> 16) & 63;
            atomicAdd(&lcnt[rld[k]], 1);
        }
    }
    __syncthreads();
    int cv = (t < 64) ? lcnt[t] : 0;
    if (t < 64) arr[t] = cv;
    __syncthreads();
    for (int off = 1; off < 64; off <<= 1) {
        int x = 0, a = 0;
        if (t < 64) {
            x = arr[t];
            a = (t >= off) ? arr[t - off] : 0;
        }
        __syncthreads();
        if (t < 64) arr[t] = x + a;
        __syncthreads();
    }
    if (t < 64) {
        loff[t] = arr[t] - cv;
        lcur[t] = arr[t] - cv;
    }
    if (t == 63) loff[64] = arr[63];
    __syncthreads();
    // phase B: scatter regs into LDS sorted by local dst
#pragma unroll
    for (int k = 0; k < 3; k++) {
        if (rld[k] >= 0) {
            int p = atomicAdd(&lcur[rld[k]], 1);
            sstore[p] = rc[k];
        }
    }
    __syncthreads();
    // phase C: 8 waves x 8 nodes; per node 16 lanes x 4 edge-slots in flight
    const int wv = t >> 6, lane = t & 63;
    const int grp = lane >> 4, l16 = lane & 15;
#pragma unroll
    for (int i = 0; i < 8; i++) {
        int n = wv * 8 + i;
        int node = b * 64 + n;
        int e0 = loff[n], e1 = loff[n + 1];
        float a0 = 0.f, a1 = 0.f, a2 = 0.f, a3 = 0.f;
        float a4 = 0.f, a5 = 0.f, a6 = 0.f, a7 = 0.f;
        float wsum = 0.f;
        for (int j = e0 + grp; j < e1; j += 4) {
            int2 r = sstore[j];
            float wvv = __int_as_float(r.x);
            int srcn = r.y & 0xFFFF;
            const us8 f = *(const us8*)(featb + (size_t)srcn * DD + l16 * 8);
            a0 = fmaf(bf2f(f[0]), wvv, a0);
            a1 = fmaf(bf2f(f[1]), wvv, a1);
            a2 = fmaf(bf2f(f[2]), wvv, a2);
            a3 = fmaf(bf2f(f[3]), wvv, a3);
            a4 = fmaf(bf2f(f[4]), wvv, a4);
            a5 = fmaf(bf2f(f[5]), wvv, a5);
            a6 = fmaf(bf2f(f[6]), wvv, a6);
            a7 = fmaf(bf2f(f[7]), wvv, a7);
            wsum += wvv;
        }
        float acc[8] = {a0, a1, a2, a3, a4, a5, a6, a7};
#pragma unroll
        for (int k = 0; k < 8; k++) {
            acc[k] += __shfl_xor(acc[k], 16);
            acc[k] += __shfl_xor(acc[k], 32);
        }
        wsum += __shfl_xor(wsum, 16);
        wsum += __shfl_xor(wsum, 32);
        if (grp == 0 && node < NN) {
            float inv = 1.0f / (wsum + 1e-8f);
            us8 o;
#pragma unroll
            for (int k = 0; k < 8; k++) o[k] = f2bf(acc[k] * inv);
            *(us8*)(nrmb + (size_t)node * DD + l16 * 8) = o;
        }
    }
}

// ---- K4: MFMA GEMM, LDS weights, replicated BN partials ---------------------
__global__ __launch_bounds__(256) void k_gemm(const unsigned short* __restrict__ featb,
                                              const unsigned short* __restrict__ nrmb,
                                              const unsigned short* __restrict__ Wpk,
                                              const float* __restrict__ bcomb,
                                              unsigned short* __restrict__ rstb,
                                              float* __restrict__ colrep) {
    __shared__ unsigned short sW[16384];  // 32 KB: one K-half of packed W
    __shared__ float pS[4][128];
    __shared__ float pQ[4][128];
    const int tid = threadIdx.x;
    const int wv = tid >> 6, lane = tid & 63;
    const int quad = lane >> 4, l16 = lane & 15;
    const int rowA = blockIdx.x * 64 + wv * 16 + l16;
    const bool validA = rowA < NN;

    f32x4 acc[8];
#pragma unroll
    for (int ct = 0; ct < 8; ct++) acc[ct] = (f32x4){0.f, 0.f, 0.f, 0.f};

#pragma unroll
    for (int half = 0; half < 2; half++) {
        const unsigned short* xb = half ? nrmb : featb;
        bf16x8 a[4];
#pragma unroll
        for (int k4 = 0; k4 < 4; k4++) {
            a[k4] = (bf16x8){0, 0, 0, 0, 0, 0, 0, 0};
            if (validA) a[k4] = *(const bf16x8*)(xb + (size_t)rowA * DD + k4 * 32 + quad * 8);
        }
        if (half) __syncthreads();
#pragma unroll
        for (int p = 0; p < 8; p++) {
            *(us8*)(sW + p * 2048 + tid * 8) =
                *(const us8*)(Wpk + half * 16384 + p * 2048 + tid * 8);
        }
        __syncthreads();
#pragma unroll
        for (int k4 = 0; k4 < 4; k4++) {
#pragma unroll
            for (int ct = 0; ct < 8; ct++) {
                bf16x8 bfr = *(const bf16x8*)(sW + ((k4 * 8 + ct) * 64 + lane) * 8);
                acc[ct] = __builtin_amdgcn_mfma_f32_16x16x32_bf16(a[k4], bfr, acc[ct], 0, 0, 0);
            }
        }
    }

    const int rowC = blockIdx.x * 64 + wv * 16 + quad * 4;
    float s[8], q[8];
#pragma unroll
    for (int ct = 0; ct < 8; ct++) {
        const int c = ct * 16 + l16;
        const float bb = bcomb[c];
        float ls = 0.f, lq = 0.f;
#pragma unroll
        for (int r = 0; r < 4; r++) {
            float v = acc[ct][r] + bb;
            v = v > 0.f ? v : 0.f;
            if (rowC + r < NN) {
                rstb[(size_t)(rowC + r) * DD + c] = f2bf(v);
                ls += v;
                lq += v * v;
            }
        }
        s[ct] = ls;
        q[ct] = lq;
    }
#pragma unroll
    for (int ct = 0; ct < 8; ct++) {
        s[ct] += __shfl_xor(s[ct], 16);
        s[ct] += __shfl_xor(s[ct], 32);
        q[ct] += __shfl_xor(q[ct], 16);
        q[ct] += __shfl_xor(q[ct], 32);
    }
    if (quad == 0) {
#pragma unroll
        for (int ct = 0; ct < 8; ct++) {
            pS[wv][ct * 16 + l16] = s[ct];
            pQ[wv][ct * 16 + l16] = q[ct];
        }
    }
    __syncthreads();
    if (tid < 128) {
        float* rep = colrep + (blockIdx.x & (CREP - 1)) * 256;
        float ts = pS[0][tid] + pS[1][tid] + pS[2][tid] + pS[3][tid];
        float tq = pQ[0][tid] + pQ[1][tid] + pQ[2][tid] + pQ[3][tid];
        atomicAdd(&rep[tid], ts);
        atomicAdd(&rep[128 + tid], tq);
    }
}

// ---- K5: finalize BN scale/shift (reduces CREP replicas) --------------------
__global__ void k_bnfin(const float* __restrict__ colrep,
                        const float* __restrict__ gamma, const float* __restrict__ beta,
                        float* __restrict__ scale, float* __restrict__ shift) {
    int c = threadIdx.x;
    if (c < DD) {
        float ts = 0.f, tq = 0.f;
#pragma unroll
        for (int r = 0; r < CREP; r++) {
            ts += colrep[r * 256 + c];
            tq += colrep[r * 256 + 128 + c];
        }
        float mu = ts * (1.0f / NN);
        float var = tq * (1.0f / NN) - mu * mu;
        float sc = gamma[c] * rsqrtf(var + 1e-5f);
        scale[c] = sc;
        shift[c] = beta[c] - mu * sc;
    }
}

// ---- K6: apply BN (bf16 rst -> fp32 out) ------------------------------------
__global__ void k_apply(const unsigned short* __restrict__ rstb,
                        const float* __restrict__ scale, const float* __restrict__ shift,
                        float* __restrict__ out) {
    int idx = blockIdx.x * 256 + threadIdx.x;
    if (idx < NN * DD / 8) {
        us8 v = *(const us8*)(rstb + (size_t)idx * 8);
        int c8 = (idx & 15) * 8;
        float4 s0 = *(const float4*)(scale + c8);
        float4 s1 = *(const float4*)(scale + c8 + 4);
        float4 h0 = *(const float4*)(shift + c8);
        float4 h1 = *(const float4*)(shift + c8 + 4);
        float4 o0, o1;
        o0.x = fmaf(bf2f(v[0]), s0.x, h0.x);
        o0.y = fmaf(bf2f(v[1]), s0.y, h0.y);
        o0.z = fmaf(bf2f(v[2]), s0.z, h0.z);
        o0.w = fmaf(bf2f(v[3]), s0.w, h0.w);
        o1.x = fmaf(bf2f(v[4]), s1.x, h1.x);
        o1.y = fmaf(bf2f(v[5]), s1.y, h1.y);
        o1.z = fmaf(bf2f(v[6]), s1.z, h1.z);
        o1.w = fmaf(bf2f(v[7]), s1.w, h1.w);
        ((float4*)out)[idx * 2] = o0;
        ((float4*)out)[idx * 2 + 1] = o1;
    }
}

extern "C" void kernel_launch(void* const* d_in, const int* in_sizes, int n_in,
                              void* d_out, int out_size, void* d_ws, size_t ws_size,
                              hipStream_t stream) {
    const float* feat = (const float*)d_in[0];
    const int* src = (const int*)d_in[1];
    const int* dst = (const int*)d_in[2];
    const float* ew = (const float*)d_in[3];
    const float* Wneigh = (const float*)d_in[4];
    const float* Wself = (const float*)d_in[5];
    const float* bself = (const float*)d_in[6];
    const float* bias = (const float*)d_in[7];
    const float* gamma = (const float*)d_in[8];
    const float* beta = (const float*)d_in[9];
    float* out = (float*)d_out;

    float* ws = (float*)d_ws;
    unsigned short* featb = (unsigned short*)ws;             // 6.4M bf16
    unsigned short* nrmb = (unsigned short*)(ws + 3200000);  // 6.4M bf16
    unsigned short* Wpk = (unsigned short*)(ws + 6400000);   // 32768 bf16
    float* bcomb = ws + 6416384;                             // 128
    float* scale = bcomb + 128;                              // 128
    float* shift = scale + 128;                              // 128
    int* ghist = (int*)(shift + 128);                        // 16*783  [zeroed]
    float* colrep = (float*)(ghist + HREP * (NBK + 1));      // 64*256  [zeroed]
    int* bbase = (int*)(colrep + CREP * 256);                // 783
    int* bcursor = bbase + 783;                              // 782 (+1 pad)
    int2* binned = (int2*)(bcursor + 784);                   // 800000 x 8B
    unsigned short* rstb = featb;  // alias: gemm reads/writes same rows per tile

    hipMemsetAsync(ghist, 0, (HREP * (NBK + 1) + CREP * 256) * sizeof(int), stream);

    k_pre<<<CVT_NB + HIST_NB, 256, 0, stream>>>(feat, featb, dst, ghist);
    k_scanp<<<9, 512, 0, stream>>>(ghist, bbase, bcursor, Wneigh, Wself, bself, bias,
                                   Wpk, bcomb);
    k_bin<<<BIN_NB, 512, 0, stream>>>(src, dst, ew, bcursor, binned);
    k_aggr2<<<NBK, 512, 0, stream>>>(featb, bbase, binned, nrmb);
    k_gemm<<<(NN + 63) / 64, 256, 0, stream>>>(featb, nrmb, Wpk, bcomb, rstb, colrep);
    k_bnfin<<<1, 128, 0, stream>>>(colrep, gamma, beta, scale, shift);
    k_apply<<<(NN * DD / 8 + 255) / 256, 256, 0, stream>>>(rstb, scale, shift, out);
}